// Round 5
// baseline (753.629 us; speedup 1.0000x reference)
//
#include <hip/hip_runtime.h>
#include <math.h>

#define BB 32
#define CC 512
#define CR 32
#define HWN 3136
#define HW4 784   // HWN / 4

typedef float f32x4 __attribute__((ext_vector_type(4)));

// ---------------------------------------------------------------------------
// Fused kernel: one block per (b,c) plane-pair (R2-proven structure):
//   - sum of xr/xi plane -> ar/ai ; argmax of score^2 -> carried (r,q) values
//   - release-fence + atomicAdd(cnt[b]); the 512th block of batch b runs the
//     whole complex-MLP for that batch in-place (no second dispatch).
// score^2 = zr^2+zi^2 = fma(fma(d,u, 2(r^2-q^2)), u, d), u = rcp(d), d=r^2+q^2
// (fast rcp feeds the argmax only; outputs are exact carried values)
// ---------------------------------------------------------------------------
__global__ __launch_bounds__(256) void cg_fused_kernel(
    const float* __restrict__ x,
    float* __restrict__ ws, int* __restrict__ cnt,
    const float* __restrict__ w1r, const float* __restrict__ b1r,
    const float* __restrict__ w1i, const float* __restrict__ b1i,
    const float* __restrict__ w2r, const float* __restrict__ b2r,
    const float* __restrict__ w2i, const float* __restrict__ b2i,
    float* __restrict__ out)
{
    float* ar = ws;
    float* ai = ws +     BB * CC;
    float* mr = ws + 2 * BB * CC;
    float* mi = ws + 3 * BB * CC;

    const int bc = blockIdx.x;            // 0 .. B*C-1
    const int b  = bc >> 9;               // / CC
    const int c  = bc & (CC - 1);
    const float* xr = x + (size_t)((b << 10) + c) * HWN;   // (b*2C + c)*HWN
    const float* xi = xr + (size_t)CC * HWN;
    const f32x4* xr4 = (const f32x4*)xr;
    const f32x4* xi4 = (const f32x4*)xi;
    const int t = threadIdx.x;

    float sr = 0.0f, si = 0.0f;
    float bs = -1.0f;                     // best score^2 (>=0 always wins)
    int   bix = 0x7fffffff;
    float br = 0.0f, bq = 0.0f;           // carried values at best index

    for (int v = t; v < HW4; v += 256) {
        f32x4 r4 = __builtin_nontemporal_load(&xr4[v]);
        f32x4 i4 = __builtin_nontemporal_load(&xi4[v]);
#pragma unroll
        for (int k = 0; k < 4; ++k) {
            float r = r4[k], q = i4[k];
            sr += r; si += q;
            float r2 = r * r, q2 = q * q;
            float d  = r2 + q2;
            float u  = __builtin_amdgcn_rcpf(d);
            float s  = fmaf(fmaf(d, u, 2.0f * (r2 - q2)), u, d);
            int idx  = v * 4 + k;         // strictly increasing per thread
            if (s > bs) { bs = s; bix = idx; br = r; bq = q; }
        }
    }

    // wave-level reduce (wave = 64); ties -> min index (jnp first-hit)
#pragma unroll
    for (int off = 32; off > 0; off >>= 1) {
        sr += __shfl_down(sr, off);
        si += __shfl_down(si, off);
        float os = __shfl_down(bs, off);
        int   oi = __shfl_down(bix, off);
        float orr = __shfl_down(br, off);
        float oq  = __shfl_down(bq, off);
        if (os > bs || (os == bs && oi < bix)) { bs = os; bix = oi; br = orr; bq = oq; }
    }

    __shared__ float lsr[4], lsi[4], lbs[4], lbr[4], lbq[4];
    __shared__ int   lbi[4];
    __shared__ int   s_last;
    const int wave = t >> 6;
    if ((t & 63) == 0) {
        lsr[wave] = sr; lsi[wave] = si; lbs[wave] = bs;
        lbi[wave] = bix; lbr[wave] = br; lbq[wave] = bq;
    }
    __syncthreads();

    if (t == 0) {
        sr = lsr[0]; si = lsi[0]; bs = lbs[0]; bix = lbi[0]; br = lbr[0]; bq = lbq[0];
#pragma unroll
        for (int w = 1; w < 4; ++w) {
            sr += lsr[w]; si += lsi[w];
            if (lbs[w] > bs || (lbs[w] == bs && lbi[w] < bix)) {
                bs = lbs[w]; bix = lbi[w]; br = lbr[w]; bq = lbq[w];
            }
        }
        ar[bc] = sr * (1.0f / HWN);
        ai[bc] = si * (1.0f / HWN);
        mr[bc] = br;
        mi[bc] = bq;
        __threadfence();                          // release partials
        int old = atomicAdd(&cnt[b], 1);          // device-scope
        s_last = (old == CC - 1) ? 1 : 0;
    }
    __syncthreads();

    if (!s_last) return;

    // ---------------- MLP phase: this block finishes batch b ----------------
    __threadfence();                              // acquire
    __shared__ __align__(16) float s_re[2][CC], s_im[2][CC];
    __shared__ float h_re[2][CR], h_im[2][CR];

    {   // volatile loads: bypass L1 (per-CU L1 not coherent across blocks)
        volatile const float* var = ar + b * CC;
        volatile const float* vai = ai + b * CC;
        volatile const float* vmr = mr + b * CC;
        volatile const float* vmi = mi + b * CC;
        for (int k = t; k < CC; k += 256) {
            s_re[0][k] = var[k];
            s_im[0][k] = vai[k];
            s_re[1][k] = vmr[k];
            s_im[1][k] = vmi[k];
        }
    }
    __syncthreads();

    // ---- layer 1 + cardioid: 64 tasks (m,j), 4 threads per task ----
    {
        const int task = t >> 2;          // 0..63
        const int part = t & 3;
        const int m = task >> 5;          // which MLP input (mean / max)
        const int j = task & 31;          // hidden unit
        const f32x4* wr4 = (const f32x4*)(w1r + j * CC + part * 128);
        const f32x4* wi4 = (const f32x4*)(w1i + j * CC + part * 128);
        const f32x4* re4 = (const f32x4*)(&s_re[m][part * 128]);
        const f32x4* im4 = (const f32x4*)(&s_im[m][part * 128]);
        float d_rr = 0.f, d_ir = 0.f, d_ri = 0.f, d_ii = 0.f;
#pragma unroll 8
        for (int k = 0; k < 32; ++k) {
            f32x4 re = re4[k], im = im4[k], vr = wr4[k], vi = wi4[k];
#pragma unroll
            for (int kk = 0; kk < 4; ++kk) {
                d_rr += re[kk] * vr[kk];
                d_ir += im[kk] * vr[kk];
                d_ri += re[kk] * vi[kk];
                d_ii += im[kk] * vi[kk];
            }
        }
        d_rr += __shfl_xor(d_rr, 1); d_rr += __shfl_xor(d_rr, 2);
        d_ir += __shfl_xor(d_ir, 1); d_ir += __shfl_xor(d_ir, 2);
        d_ri += __shfl_xor(d_ri, 1); d_ri += __shfl_xor(d_ri, 2);
        d_ii += __shfl_xor(d_ii, 1); d_ii += __shfl_xor(d_ii, 2);
        if (part == 0) {
            float hre = d_rr + b1r[j] - d_ii - b1i[j];
            float him = d_ir + b1r[j] + d_ri + b1i[j];
            // cardioid: s = 0.5*(1 + cos(atan2(im,re))) = 0.5*(1 + re/|z|)
            float n2 = hre * hre + him * him;
            float s  = (n2 > 0.0f) ? 0.5f * (1.0f + hre * rsqrtf(n2)) : 1.0f;
            h_re[m][j] = hre * s;
            h_im[m][j] = him * s;
        }
    }
    __syncthreads();

    // ---- layer 2 (summed over both MLPs) ----
    for (int j = t; j < CC; j += 256) {
        float o_re = 2.0f * (b2r[j] - b2i[j]);   // bias applied per MLP (x2)
        float o_im = 2.0f * (b2r[j] + b2i[j]);
        const f32x4* wr4 = (const f32x4*)(w2r + j * CR);
        const f32x4* wi4 = (const f32x4*)(w2i + j * CR);
#pragma unroll
        for (int m = 0; m < 2; ++m) {
            const float* hr_ = h_re[m];
            const float* hi_ = h_im[m];
#pragma unroll
            for (int kv = 0; kv < 8; ++kv) {
                f32x4 vr = wr4[kv], vi = wi4[kv];
#pragma unroll
                for (int kk = 0; kk < 4; ++kk) {
                    float hr = hr_[kv * 4 + kk], hi = hi_[kv * 4 + kk];
                    o_re += hr * vr[kk] - hi * vi[kk];
                    o_im += hi * vr[kk] + hr * vi[kk];
                }
            }
        }
        out[b * 2 * CC + j]      = o_re;
        out[b * 2 * CC + CC + j] = o_im;
    }
}

extern "C" void kernel_launch(void* const* d_in, const int* in_sizes, int n_in,
                              void* d_out, int out_size, void* d_ws, size_t ws_size,
                              hipStream_t stream)
{
    const float* x   = (const float*)d_in[0];
    const float* w1r = (const float*)d_in[1];
    const float* b1r = (const float*)d_in[2];
    const float* w1i = (const float*)d_in[3];
    const float* b1i = (const float*)d_in[4];
    const float* w2r = (const float*)d_in[5];
    const float* b2r = (const float*)d_in[6];
    const float* w2i = (const float*)d_in[7];
    const float* b2i = (const float*)d_in[8];

    float* ws  = (float*)d_ws;
    int*   cnt = (int*)(ws + 4 * BB * CC);

    hipMemsetAsync(cnt, 0, BB * sizeof(int), stream);
    cg_fused_kernel<<<BB * CC, 256, 0, stream>>>(x, ws, cnt,
                                                 w1r, b1r, w1i, b1i,
                                                 w2r, b2r, w2i, b2i,
                                                 (float*)d_out);
}

// Round 6
// 243.537 us; speedup vs baseline: 3.0945x; 3.0945x over previous
//
#include <hip/hip_runtime.h>
#include <math.h>

#define BB 32
#define CC 512
#define CR 32
#define HWN 3136
#define HW4 784   // HWN / 4

typedef float f32x4 __attribute__((ext_vector_type(4)));

// ---------------------------------------------------------------------------
// Fused kernel, FENCE-FREE handshake (R4's __threadfence caused 16384 L2
// cache-maintenance walks -> 753us). Partials are published/consumed with
// agent-scope relaxed atomics (sc0/sc1 write-through to MALL, coherent across
// XCDs, no cache ops); ordering store->counter via one s_waitcnt vmcnt(0).
//   - block per (b,c): plane sums -> ar/ai; argmax of score^2 with carried
//     (r,q) values -> mr/mi  (fast rcp feeds argmax only)
//   - 512th block of batch b runs the complex MLP for that batch.
// ---------------------------------------------------------------------------
__global__ __launch_bounds__(256) void cg_fused_kernel(
    const float* __restrict__ x,
    float* __restrict__ ws, int* __restrict__ cnt,
    const float* __restrict__ w1r, const float* __restrict__ b1r,
    const float* __restrict__ w1i, const float* __restrict__ b1i,
    const float* __restrict__ w2r, const float* __restrict__ b2r,
    const float* __restrict__ w2i, const float* __restrict__ b2i,
    float* __restrict__ out)
{
    float* ar = ws;
    float* ai = ws +     BB * CC;
    float* mr = ws + 2 * BB * CC;
    float* mi = ws + 3 * BB * CC;

    const int bc = blockIdx.x;            // 0 .. B*C-1
    const int b  = bc >> 9;               // / CC
    const int c  = bc & (CC - 1);
    const float* xr = x + (size_t)((b << 10) + c) * HWN;   // (b*2C + c)*HWN
    const float* xi = xr + (size_t)CC * HWN;
    const f32x4* xr4 = (const f32x4*)xr;
    const f32x4* xi4 = (const f32x4*)xi;
    const int t = threadIdx.x;

    float sr = 0.0f, si = 0.0f;
    float bs = -1.0f;                     // best score^2 (>=0 always wins)
    int   bix = 0x7fffffff;
    float br = 0.0f, bq = 0.0f;           // carried values at best index

    for (int v = t; v < HW4; v += 256) {
        f32x4 r4 = __builtin_nontemporal_load(&xr4[v]);
        f32x4 i4 = __builtin_nontemporal_load(&xi4[v]);
#pragma unroll
        for (int k = 0; k < 4; ++k) {
            float r = r4[k], q = i4[k];
            sr += r; si += q;
            float r2 = r * r, q2 = q * q;
            float d  = r2 + q2;
            float u  = __builtin_amdgcn_rcpf(d);
            float s  = fmaf(fmaf(d, u, 2.0f * (r2 - q2)), u, d);
            int idx  = v * 4 + k;         // strictly increasing per thread
            if (s > bs) { bs = s; bix = idx; br = r; bq = q; }
        }
    }

    // wave-level reduce (wave = 64); ties -> min index (jnp first-hit)
#pragma unroll
    for (int off = 32; off > 0; off >>= 1) {
        sr += __shfl_down(sr, off);
        si += __shfl_down(si, off);
        float os = __shfl_down(bs, off);
        int   oi = __shfl_down(bix, off);
        float orr = __shfl_down(br, off);
        float oq  = __shfl_down(bq, off);
        if (os > bs || (os == bs && oi < bix)) { bs = os; bix = oi; br = orr; bq = oq; }
    }

    __shared__ float lsr[4], lsi[4], lbs[4], lbr[4], lbq[4];
    __shared__ int   lbi[4];
    __shared__ int   s_last;
    const int wave = t >> 6;
    if ((t & 63) == 0) {
        lsr[wave] = sr; lsi[wave] = si; lbs[wave] = bs;
        lbi[wave] = bix; lbr[wave] = br; lbq[wave] = bq;
    }
    __syncthreads();

    if (t == 0) {
        sr = lsr[0]; si = lsi[0]; bs = lbs[0]; bix = lbi[0]; br = lbr[0]; bq = lbq[0];
#pragma unroll
        for (int w = 1; w < 4; ++w) {
            sr += lsr[w]; si += lsi[w];
            if (lbs[w] > bs || (lbs[w] == bs && lbi[w] < bix)) {
                bs = lbs[w]; bix = lbi[w]; br = lbr[w]; bq = lbq[w];
            }
        }
        // publish partials: agent-scope write-through (coherent at MALL)
        __hip_atomic_store(&ar[bc], sr * (1.0f / HWN), __ATOMIC_RELAXED, __HIP_MEMORY_SCOPE_AGENT);
        __hip_atomic_store(&ai[bc], si * (1.0f / HWN), __ATOMIC_RELAXED, __HIP_MEMORY_SCOPE_AGENT);
        __hip_atomic_store(&mr[bc], br,                __ATOMIC_RELAXED, __HIP_MEMORY_SCOPE_AGENT);
        __hip_atomic_store(&mi[bc], bq,                __ATOMIC_RELAXED, __HIP_MEMORY_SCOPE_AGENT);
        asm volatile("s_waitcnt vmcnt(0)" ::: "memory");   // stores reached MALL
        int old = __hip_atomic_fetch_add(&cnt[b], 1, __ATOMIC_RELAXED, __HIP_MEMORY_SCOPE_AGENT);
        s_last = (old == CC - 1) ? 1 : 0;
    }
    __syncthreads();

    if (!s_last) return;

    // ---------------- MLP phase: this block finishes batch b ----------------
    __shared__ __align__(16) float s_re[2][CC], s_im[2][CC];
    __shared__ float h_re[2][CR], h_im[2][CR];

    for (int k = t; k < CC; k += 256) {   // agent-scope loads: read from MALL
        s_re[0][k] = __hip_atomic_load(&ar[b * CC + k], __ATOMIC_RELAXED, __HIP_MEMORY_SCOPE_AGENT);
        s_im[0][k] = __hip_atomic_load(&ai[b * CC + k], __ATOMIC_RELAXED, __HIP_MEMORY_SCOPE_AGENT);
        s_re[1][k] = __hip_atomic_load(&mr[b * CC + k], __ATOMIC_RELAXED, __HIP_MEMORY_SCOPE_AGENT);
        s_im[1][k] = __hip_atomic_load(&mi[b * CC + k], __ATOMIC_RELAXED, __HIP_MEMORY_SCOPE_AGENT);
    }
    __syncthreads();

    // ---- layer 1 + cardioid: 64 tasks (m,j), 4 threads per task ----
    {
        const int task = t >> 2;          // 0..63
        const int part = t & 3;
        const int m = task >> 5;          // which MLP input (mean / max)
        const int j = task & 31;          // hidden unit
        const f32x4* wr4 = (const f32x4*)(w1r + j * CC + part * 128);
        const f32x4* wi4 = (const f32x4*)(w1i + j * CC + part * 128);
        const f32x4* re4 = (const f32x4*)(&s_re[m][part * 128]);
        const f32x4* im4 = (const f32x4*)(&s_im[m][part * 128]);
        float d_rr = 0.f, d_ir = 0.f, d_ri = 0.f, d_ii = 0.f;
#pragma unroll 8
        for (int k = 0; k < 32; ++k) {
            f32x4 re = re4[k], im = im4[k], vr = wr4[k], vi = wi4[k];
#pragma unroll
            for (int kk = 0; kk < 4; ++kk) {
                d_rr += re[kk] * vr[kk];
                d_ir += im[kk] * vr[kk];
                d_ri += re[kk] * vi[kk];
                d_ii += im[kk] * vi[kk];
            }
        }
        d_rr += __shfl_xor(d_rr, 1); d_rr += __shfl_xor(d_rr, 2);
        d_ir += __shfl_xor(d_ir, 1); d_ir += __shfl_xor(d_ir, 2);
        d_ri += __shfl_xor(d_ri, 1); d_ri += __shfl_xor(d_ri, 2);
        d_ii += __shfl_xor(d_ii, 1); d_ii += __shfl_xor(d_ii, 2);
        if (part == 0) {
            float hre = d_rr + b1r[j] - d_ii - b1i[j];
            float him = d_ir + b1r[j] + d_ri + b1i[j];
            // cardioid: s = 0.5*(1 + cos(atan2(im,re))) = 0.5*(1 + re/|z|)
            float n2 = hre * hre + him * him;
            float s  = (n2 > 0.0f) ? 0.5f * (1.0f + hre * rsqrtf(n2)) : 1.0f;
            h_re[m][j] = hre * s;
            h_im[m][j] = him * s;
        }
    }
    __syncthreads();

    // ---- layer 2 (summed over both MLPs) ----
    for (int j = t; j < CC; j += 256) {
        float o_re = 2.0f * (b2r[j] - b2i[j]);   // bias applied per MLP (x2)
        float o_im = 2.0f * (b2r[j] + b2i[j]);
        const f32x4* wr4 = (const f32x4*)(w2r + j * CR);
        const f32x4* wi4 = (const f32x4*)(w2i + j * CR);
#pragma unroll
        for (int m = 0; m < 2; ++m) {
            const float* hr_ = h_re[m];
            const float* hi_ = h_im[m];
#pragma unroll
            for (int kv = 0; kv < 8; ++kv) {
                f32x4 vr = wr4[kv], vi = wi4[kv];
#pragma unroll
                for (int kk = 0; kk < 4; ++kk) {
                    float hr = hr_[kv * 4 + kk], hi = hi_[kv * 4 + kk];
                    o_re += hr * vr[kk] - hi * vi[kk];
                    o_im += hi * vr[kk] + hr * vi[kk];
                }
            }
        }
        out[b * 2 * CC + j]      = o_re;
        out[b * 2 * CC + CC + j] = o_im;
    }
}

extern "C" void kernel_launch(void* const* d_in, const int* in_sizes, int n_in,
                              void* d_out, int out_size, void* d_ws, size_t ws_size,
                              hipStream_t stream)
{
    const float* x   = (const float*)d_in[0];
    const float* w1r = (const float*)d_in[1];
    const float* b1r = (const float*)d_in[2];
    const float* w1i = (const float*)d_in[3];
    const float* b1i = (const float*)d_in[4];
    const float* w2r = (const float*)d_in[5];
    const float* b2r = (const float*)d_in[6];
    const float* w2i = (const float*)d_in[7];
    const float* b2i = (const float*)d_in[8];

    float* ws  = (float*)d_ws;
    int*   cnt = (int*)(ws + 4 * BB * CC);

    hipMemsetAsync(cnt, 0, BB * sizeof(int), stream);
    cg_fused_kernel<<<BB * CC, 256, 0, stream>>>(x, ws, cnt,
                                                 w1r, b1r, w1i, b1i,
                                                 w2r, b2r, w2i, b2i,
                                                 (float*)d_out);
}

// Round 7
// 201.434 us; speedup vs baseline: 3.7413x; 1.2090x over previous
//
#include <hip/hip_runtime.h>
#include <math.h>

#define BB 32
#define CC 512
#define CR 32
#define HWN 3136
#define HW4 784   // HWN / 4

typedef float f32x4 __attribute__((ext_vector_type(4)));

#define AGENT __HIP_MEMORY_SCOPE_AGENT

// ---------------------------------------------------------------------------
// Fused kernel, fence-free + CONTENTION-FREE handshake.
// R4: __threadfence per block = 16k L2 cache walks (753us).
// R5: relaxed agent atomics, but 16384 fetch_adds on 32 ints in ONE cache
//     line -> serialized at the MALL (~240us).
// R6: hierarchical counters. 8 sub-counters per batch (64 blocks each), each
//     padded to its own 256B line (256 lines spread over MALL slices, RMW
//     depth 64, arrival staggered over the 65us stream -> hidden). Sub-winner
//     bumps a padded batch counter (depth 8); its winner runs the MLP.
// ---------------------------------------------------------------------------
__global__ __launch_bounds__(256) void cg_fused_kernel(
    const float* __restrict__ x,
    float* __restrict__ ws, int* __restrict__ cnt,
    const float* __restrict__ w1r, const float* __restrict__ b1r,
    const float* __restrict__ w1i, const float* __restrict__ b1i,
    const float* __restrict__ w2r, const float* __restrict__ b2r,
    const float* __restrict__ w2i, const float* __restrict__ b2i,
    float* __restrict__ out)
{
    float* ar = ws;
    float* ai = ws +     BB * CC;
    float* mr = ws + 2 * BB * CC;
    float* mi = ws + 3 * BB * CC;
    int* cnt_sub = cnt;                   // [(b*8+s)*64] : 16384 ints
    int* cnt_bat = cnt + BB * 8 * 64;     // [b*64]       :  2048 ints

    const int bc = blockIdx.x;            // 0 .. B*C-1
    const int b  = bc >> 9;               // / CC
    const int c  = bc & (CC - 1);
    const float* xr = x + (size_t)((b << 10) + c) * HWN;   // (b*2C + c)*HWN
    const float* xi = xr + (size_t)CC * HWN;
    const f32x4* xr4 = (const f32x4*)xr;
    const f32x4* xi4 = (const f32x4*)xi;
    const int t = threadIdx.x;

    float sr = 0.0f, si = 0.0f;
    float bs = -1.0f;                     // best score^2 (>=0 always wins)
    int   bix = 0x7fffffff;
    float br = 0.0f, bq = 0.0f;           // carried values at best index

    for (int v = t; v < HW4; v += 256) {
        f32x4 r4 = __builtin_nontemporal_load(&xr4[v]);
        f32x4 i4 = __builtin_nontemporal_load(&xi4[v]);
#pragma unroll
        for (int k = 0; k < 4; ++k) {
            float r = r4[k], q = i4[k];
            sr += r; si += q;
            float r2 = r * r, q2 = q * q;
            float d  = r2 + q2;
            float u  = __builtin_amdgcn_rcpf(d);
            float s  = fmaf(fmaf(d, u, 2.0f * (r2 - q2)), u, d);
            int idx  = v * 4 + k;         // strictly increasing per thread
            if (s > bs) { bs = s; bix = idx; br = r; bq = q; }
        }
    }

    // wave-level reduce (wave = 64); ties -> min index (jnp first-hit)
#pragma unroll
    for (int off = 32; off > 0; off >>= 1) {
        sr += __shfl_down(sr, off);
        si += __shfl_down(si, off);
        float os = __shfl_down(bs, off);
        int   oi = __shfl_down(bix, off);
        float orr = __shfl_down(br, off);
        float oq  = __shfl_down(bq, off);
        if (os > bs || (os == bs && oi < bix)) { bs = os; bix = oi; br = orr; bq = oq; }
    }

    __shared__ float lsr[4], lsi[4], lbs[4], lbr[4], lbq[4];
    __shared__ int   lbi[4];
    __shared__ int   s_last;
    const int wave = t >> 6;
    if ((t & 63) == 0) {
        lsr[wave] = sr; lsi[wave] = si; lbs[wave] = bs;
        lbi[wave] = bix; lbr[wave] = br; lbq[wave] = bq;
    }
    __syncthreads();

    if (t == 0) {
        sr = lsr[0]; si = lsi[0]; bs = lbs[0]; bix = lbi[0]; br = lbr[0]; bq = lbq[0];
#pragma unroll
        for (int w = 1; w < 4; ++w) {
            sr += lsr[w]; si += lsi[w];
            if (lbs[w] > bs || (lbs[w] == bs && lbi[w] < bix)) {
                bs = lbs[w]; bix = lbi[w]; br = lbr[w]; bq = lbq[w];
            }
        }
        // publish partials: agent-scope write-through (coherent at MALL)
        __hip_atomic_store(&ar[bc], sr * (1.0f / HWN), __ATOMIC_RELAXED, AGENT);
        __hip_atomic_store(&ai[bc], si * (1.0f / HWN), __ATOMIC_RELAXED, AGENT);
        __hip_atomic_store(&mr[bc], br,                __ATOMIC_RELAXED, AGENT);
        __hip_atomic_store(&mi[bc], bq,                __ATOMIC_RELAXED, AGENT);
        asm volatile("s_waitcnt vmcnt(0)" ::: "memory");   // stores at MALL
        // hierarchical completion count (each counter on its own 256B line)
        int last = 0;
        int old = __hip_atomic_fetch_add(&cnt_sub[((b << 3) | (c >> 6)) << 6], 1,
                                         __ATOMIC_RELAXED, AGENT);
        if (old == 63) {
            int old2 = __hip_atomic_fetch_add(&cnt_bat[b << 6], 1,
                                              __ATOMIC_RELAXED, AGENT);
            last = (old2 == 7) ? 1 : 0;
        }
        s_last = last;
    }
    __syncthreads();

    if (!s_last) return;

    // ---------------- MLP phase: this block finishes batch b ----------------
    __shared__ __align__(16) float s_re[2][CC], s_im[2][CC];
    __shared__ float h_re[2][CR], h_im[2][CR];

    for (int k = t; k < CC; k += 256) {   // agent-scope loads: read from MALL
        s_re[0][k] = __hip_atomic_load(&ar[b * CC + k], __ATOMIC_RELAXED, AGENT);
        s_im[0][k] = __hip_atomic_load(&ai[b * CC + k], __ATOMIC_RELAXED, AGENT);
        s_re[1][k] = __hip_atomic_load(&mr[b * CC + k], __ATOMIC_RELAXED, AGENT);
        s_im[1][k] = __hip_atomic_load(&mi[b * CC + k], __ATOMIC_RELAXED, AGENT);
    }
    __syncthreads();

    // ---- layer 1 + cardioid: 64 tasks (m,j), 4 threads per task ----
    {
        const int task = t >> 2;          // 0..63
        const int part = t & 3;
        const int m = task >> 5;          // which MLP input (mean / max)
        const int j = task & 31;          // hidden unit
        const f32x4* wr4 = (const f32x4*)(w1r + j * CC + part * 128);
        const f32x4* wi4 = (const f32x4*)(w1i + j * CC + part * 128);
        const f32x4* re4 = (const f32x4*)(&s_re[m][part * 128]);
        const f32x4* im4 = (const f32x4*)(&s_im[m][part * 128]);
        float d_rr = 0.f, d_ir = 0.f, d_ri = 0.f, d_ii = 0.f;
#pragma unroll 8
        for (int k = 0; k < 32; ++k) {
            f32x4 re = re4[k], im = im4[k], vr = wr4[k], vi = wi4[k];
#pragma unroll
            for (int kk = 0; kk < 4; ++kk) {
                d_rr += re[kk] * vr[kk];
                d_ir += im[kk] * vr[kk];
                d_ri += re[kk] * vi[kk];
                d_ii += im[kk] * vi[kk];
            }
        }
        d_rr += __shfl_xor(d_rr, 1); d_rr += __shfl_xor(d_rr, 2);
        d_ir += __shfl_xor(d_ir, 1); d_ir += __shfl_xor(d_ir, 2);
        d_ri += __shfl_xor(d_ri, 1); d_ri += __shfl_xor(d_ri, 2);
        d_ii += __shfl_xor(d_ii, 1); d_ii += __shfl_xor(d_ii, 2);
        if (part == 0) {
            float hre = d_rr + b1r[j] - d_ii - b1i[j];
            float him = d_ir + b1r[j] + d_ri + b1i[j];
            // cardioid: s = 0.5*(1 + cos(atan2(im,re))) = 0.5*(1 + re/|z|)
            float n2 = hre * hre + him * him;
            float s  = (n2 > 0.0f) ? 0.5f * (1.0f + hre * rsqrtf(n2)) : 1.0f;
            h_re[m][j] = hre * s;
            h_im[m][j] = him * s;
        }
    }
    __syncthreads();

    // ---- layer 2 (summed over both MLPs) ----
    for (int j = t; j < CC; j += 256) {
        float o_re = 2.0f * (b2r[j] - b2i[j]);   // bias applied per MLP (x2)
        float o_im = 2.0f * (b2r[j] + b2i[j]);
        const f32x4* wr4 = (const f32x4*)(w2r + j * CR);
        const f32x4* wi4 = (const f32x4*)(w2i + j * CR);
#pragma unroll
        for (int m = 0; m < 2; ++m) {
            const float* hr_ = h_re[m];
            const float* hi_ = h_im[m];
#pragma unroll
            for (int kv = 0; kv < 8; ++kv) {
                f32x4 vr = wr4[kv], vi = wi4[kv];
#pragma unroll
                for (int kk = 0; kk < 4; ++kk) {
                    float hr = hr_[kv * 4 + kk], hi = hi_[kv * 4 + kk];
                    o_re += hr * vr[kk] - hi * vi[kk];
                    o_im += hi * vr[kk] + hr * vi[kk];
                }
            }
        }
        out[b * 2 * CC + j]      = o_re;
        out[b * 2 * CC + CC + j] = o_im;
    }
}

extern "C" void kernel_launch(void* const* d_in, const int* in_sizes, int n_in,
                              void* d_out, int out_size, void* d_ws, size_t ws_size,
                              hipStream_t stream)
{
    const float* x   = (const float*)d_in[0];
    const float* w1r = (const float*)d_in[1];
    const float* b1r = (const float*)d_in[2];
    const float* w1i = (const float*)d_in[3];
    const float* b1i = (const float*)d_in[4];
    const float* w2r = (const float*)d_in[5];
    const float* b2r = (const float*)d_in[6];
    const float* w2i = (const float*)d_in[7];
    const float* b2i = (const float*)d_in[8];

    float* ws  = (float*)d_ws;
    int*   cnt = (int*)(ws + 4 * BB * CC);
    const int n_cnt = BB * 8 * 64 + BB * 64;     // sub + batch counters

    hipMemsetAsync(cnt, 0, n_cnt * sizeof(int), stream);
    cg_fused_kernel<<<BB * CC, 256, 0, stream>>>(x, ws, cnt,
                                                 w1r, b1r, w1i, b1i,
                                                 w2r, b2r, w2i, b2i,
                                                 (float*)d_out);
}

// Round 8
// 168.009 us; speedup vs baseline: 4.4857x; 1.1990x over previous
//
#include <hip/hip_runtime.h>
#include <math.h>
#include <stdint.h>

#define BB 32
#define CC 512
#define CR 32
#define HWN 3136
#define HW4 784   // HWN / 4
#define NPOLL 32  // one poller block per batch, dispatched first
#define SENT 0xFFFFFFFFu   // -NaN payload: unreachable from finite inputs

typedef float f32x4 __attribute__((ext_vector_type(4)));
#define AGENT __HIP_MEMORY_SCOPE_AGENT

// ---------------------------------------------------------------------------
// R4: __threadfence/block = 16k L2 cache walks -> 753us.
// R5/R6: counter handshake -> every block's epilogue chained
//   stores -> vmcnt(0) -> RMW -> s_last broadcast (~2us) x 64 block
//   generations per CU slot ~= +130us serial tail.
// R7: FIRE-AND-FORGET workers (publish 4 relaxed agent stores, exit with no
//   wait) + 32 dedicated POLLER blocks that spin on the data itself (d_ws
//   memset to 0xFF sentinel per launch; 0xFFFFFFFF is -NaN, unreachable).
//   Pollers wait off the critical path, then run the MLP for their batch.
// ---------------------------------------------------------------------------

__device__ __forceinline__ float spin_word(const uint32_t* p) {
    uint32_t u = __hip_atomic_load(p, __ATOMIC_RELAXED, AGENT);
    while (u == SENT) {
        __builtin_amdgcn_s_sleep(16);
        u = __hip_atomic_load(p, __ATOMIC_RELAXED, AGENT);
    }
    union { uint32_t v; float f; } c; c.v = u;
    return c.f;
}

__global__ __launch_bounds__(256) void cg_fused_kernel(
    const float* __restrict__ x,
    float* __restrict__ pub,              // [B*C][4] = (ar, ai, mr, mi)
    const float* __restrict__ w1r, const float* __restrict__ b1r,
    const float* __restrict__ w1i, const float* __restrict__ b1i,
    const float* __restrict__ w2r, const float* __restrict__ b2r,
    const float* __restrict__ w2i, const float* __restrict__ b2i,
    float* __restrict__ out)
{
    const int t = threadIdx.x;

    if (blockIdx.x >= NPOLL) {
        // ======================= WORKER: one (b,c) plane-pair ==============
        const int bc = blockIdx.x - NPOLL;    // 0 .. B*C-1
        const int b  = bc >> 9;               // / CC
        const int c  = bc & (CC - 1);
        const float* xr = x + (size_t)((b << 10) + c) * HWN;
        const float* xi = xr + (size_t)CC * HWN;
        const f32x4* xr4 = (const f32x4*)xr;
        const f32x4* xi4 = (const f32x4*)xi;

        float sr = 0.0f, si = 0.0f;
        float bs = -1.0f;                     // best score^2 (>=0 always wins)
        int   bix = 0x7fffffff;
        float br = 0.0f, bq = 0.0f;           // carried values at best index

        for (int v = t; v < HW4; v += 256) {
            f32x4 r4 = __builtin_nontemporal_load(&xr4[v]);
            f32x4 i4 = __builtin_nontemporal_load(&xi4[v]);
#pragma unroll
            for (int k = 0; k < 4; ++k) {
                float r = r4[k], q = i4[k];
                sr += r; si += q;
                float r2 = r * r, q2 = q * q;
                float d  = r2 + q2;
                float u  = __builtin_amdgcn_rcpf(d);   // argmax only
                float s  = fmaf(fmaf(d, u, 2.0f * (r2 - q2)), u, d);
                int idx  = v * 4 + k;
                if (s > bs) { bs = s; bix = idx; br = r; bq = q; }
            }
        }

        // wave reduce; ties -> min index (jnp.argmax first-hit)
#pragma unroll
        for (int off = 32; off > 0; off >>= 1) {
            sr += __shfl_down(sr, off);
            si += __shfl_down(si, off);
            float os = __shfl_down(bs, off);
            int   oi = __shfl_down(bix, off);
            float orr = __shfl_down(br, off);
            float oq  = __shfl_down(bq, off);
            if (os > bs || (os == bs && oi < bix)) { bs = os; bix = oi; br = orr; bq = oq; }
        }

        __shared__ float lsr[4], lsi[4], lbs[4], lbr[4], lbq[4];
        __shared__ int   lbi[4];
        const int wave = t >> 6;
        if ((t & 63) == 0) {
            lsr[wave] = sr; lsi[wave] = si; lbs[wave] = bs;
            lbi[wave] = bix; lbr[wave] = br; lbq[wave] = bq;
        }
        __syncthreads();

        if (t == 0) {
            sr = lsr[0]; si = lsi[0]; bs = lbs[0]; bix = lbi[0]; br = lbr[0]; bq = lbq[0];
#pragma unroll
            for (int w = 1; w < 4; ++w) {
                sr += lsr[w]; si += lsi[w];
                if (lbs[w] > bs || (lbs[w] == bs && lbi[w] < bix)) {
                    bs = lbs[w]; bix = lbi[w]; br = lbr[w]; bq = lbq[w];
                }
            }
            // fire-and-forget publish: no waitcnt, no RMW, no broadcast
            float* q = pub + (size_t)bc * 4;
            __hip_atomic_store(&q[0], sr * (1.0f / HWN), __ATOMIC_RELAXED, AGENT);
            __hip_atomic_store(&q[1], si * (1.0f / HWN), __ATOMIC_RELAXED, AGENT);
            __hip_atomic_store(&q[2], br,                __ATOMIC_RELAXED, AGENT);
            __hip_atomic_store(&q[3], bq,                __ATOMIC_RELAXED, AGENT);
        }
        return;   // stores complete after endpgm; block retires at R2 pace
    }

    // ======================= POLLER: batch b = blockIdx.x ==================
    const int b = blockIdx.x;
    __shared__ __align__(16) float s_re[2][CC], s_im[2][CC];
    __shared__ float h_re[2][CR], h_im[2][CR];

    for (int k = t; k < CC; k += 256) {
        const uint32_t* q = (const uint32_t*)(pub + (size_t)(b * CC + k) * 4);
        s_re[0][k] = spin_word(q + 0);    // ar
        s_im[0][k] = spin_word(q + 1);    // ai
        s_re[1][k] = spin_word(q + 2);    // mr
        s_im[1][k] = spin_word(q + 3);    // mi
    }
    __syncthreads();

    // ---- layer 1 + cardioid: 64 tasks (m,j), 4 threads per task ----
    {
        const int task = t >> 2;          // 0..63
        const int part = t & 3;
        const int m = task >> 5;          // which MLP input (mean / max)
        const int j = task & 31;          // hidden unit
        const f32x4* wr4 = (const f32x4*)(w1r + j * CC + part * 128);
        const f32x4* wi4 = (const f32x4*)(w1i + j * CC + part * 128);
        const f32x4* re4 = (const f32x4*)(&s_re[m][part * 128]);
        const f32x4* im4 = (const f32x4*)(&s_im[m][part * 128]);
        float d_rr = 0.f, d_ir = 0.f, d_ri = 0.f, d_ii = 0.f;
#pragma unroll 8
        for (int k = 0; k < 32; ++k) {
            f32x4 re = re4[k], im = im4[k], vr = wr4[k], vi = wi4[k];
#pragma unroll
            for (int kk = 0; kk < 4; ++kk) {
                d_rr += re[kk] * vr[kk];
                d_ir += im[kk] * vr[kk];
                d_ri += re[kk] * vi[kk];
                d_ii += im[kk] * vi[kk];
            }
        }
        d_rr += __shfl_xor(d_rr, 1); d_rr += __shfl_xor(d_rr, 2);
        d_ir += __shfl_xor(d_ir, 1); d_ir += __shfl_xor(d_ir, 2);
        d_ri += __shfl_xor(d_ri, 1); d_ri += __shfl_xor(d_ri, 2);
        d_ii += __shfl_xor(d_ii, 1); d_ii += __shfl_xor(d_ii, 2);
        if (part == 0) {
            float hre = d_rr + b1r[j] - d_ii - b1i[j];
            float him = d_ir + b1r[j] + d_ri + b1i[j];
            // cardioid: s = 0.5*(1 + cos(atan2(im,re))) = 0.5*(1 + re/|z|)
            float n2 = hre * hre + him * him;
            float s  = (n2 > 0.0f) ? 0.5f * (1.0f + hre * rsqrtf(n2)) : 1.0f;
            h_re[m][j] = hre * s;
            h_im[m][j] = him * s;
        }
    }
    __syncthreads();

    // ---- layer 2 (summed over both MLPs) ----
    for (int j = t; j < CC; j += 256) {
        float o_re = 2.0f * (b2r[j] - b2i[j]);   // bias applied per MLP (x2)
        float o_im = 2.0f * (b2r[j] + b2i[j]);
        const f32x4* wr4 = (const f32x4*)(w2r + j * CR);
        const f32x4* wi4 = (const f32x4*)(w2i + j * CR);
#pragma unroll
        for (int m = 0; m < 2; ++m) {
            const float* hr_ = h_re[m];
            const float* hi_ = h_im[m];
#pragma unroll
            for (int kv = 0; kv < 8; ++kv) {
                f32x4 vr = wr4[kv], vi = wi4[kv];
#pragma unroll
                for (int kk = 0; kk < 4; ++kk) {
                    float hr = hr_[kv * 4 + kk], hi = hi_[kv * 4 + kk];
                    o_re += hr * vr[kk] - hi * vi[kk];
                    o_im += hi * vr[kk] + hr * vi[kk];
                }
            }
        }
        out[b * 2 * CC + j]      = o_re;
        out[b * 2 * CC + CC + j] = o_im;
    }
}

extern "C" void kernel_launch(void* const* d_in, const int* in_sizes, int n_in,
                              void* d_out, int out_size, void* d_ws, size_t ws_size,
                              hipStream_t stream)
{
    const float* x   = (const float*)d_in[0];
    const float* w1r = (const float*)d_in[1];
    const float* b1r = (const float*)d_in[2];
    const float* w1i = (const float*)d_in[3];
    const float* b1i = (const float*)d_in[4];
    const float* w2r = (const float*)d_in[5];
    const float* b2r = (const float*)d_in[6];
    const float* w2i = (const float*)d_in[7];
    const float* b2i = (const float*)d_in[8];

    float* pub = (float*)d_ws;                       // [B*C][4]
    const size_t pub_bytes = (size_t)BB * CC * 4 * sizeof(float);  // 256 KB

    hipMemsetAsync(pub, 0xFF, pub_bytes, stream);    // sentinel = 0xFFFFFFFF
    cg_fused_kernel<<<NPOLL + BB * CC, 256, 0, stream>>>(
        x, pub,
        w1r, b1r, w1i, b1i,
        w2r, b2r, w2i, b2i,
        (float*)d_out);
}

// Round 9
// 89.437 us; speedup vs baseline: 8.4263x; 1.8785x over previous
//
#include <hip/hip_runtime.h>
#include <math.h>
#include <stdint.h>

#define BB 32
#define CC 512
#define CR 32
#define HWN 3136
#define HW4 784   // HWN / 4
#define NPOLL 32  // one poller block per batch, dispatched first
#define SENT 0xFFFFFFFFu   // -NaN payload: unreachable from finite inputs

typedef float f32x4 __attribute__((ext_vector_type(4)));
#define AGENT __HIP_MEMORY_SCOPE_AGENT

// ---------------------------------------------------------------------------
// R4: __threadfence/block = 16k L2 cache walks -> 753us.
// R5/R6: counter handshakes -> 243/201us.
// R7: fire-and-forget workers + data-as-signal pollers -> 168us. Still 2x R2.
//     Root cause (R5 profile): fused kernel = 104 VGPR (MLP path inflates),
//     crossing the 64-VGPR occupancy cliff -> 4 waves/SIMD instead of 8 ->
//     streaming loop loses half its latency hiding.
// R8: __launch_bounds__(256, 8) caps VGPR at 64. Worker loop needs ~40;
//     the once-per-batch MLP path may spill to scratch (negligible, 32
//     blocks). Handshake unchanged from R7 (proven correct).
// ---------------------------------------------------------------------------

__device__ __forceinline__ float spin_word(const uint32_t* p) {
    uint32_t u = __hip_atomic_load(p, __ATOMIC_RELAXED, AGENT);
    while (u == SENT) {
        __builtin_amdgcn_s_sleep(16);
        u = __hip_atomic_load(p, __ATOMIC_RELAXED, AGENT);
    }
    union { uint32_t v; float f; } c; c.v = u;
    return c.f;
}

__global__ __launch_bounds__(256, 8) void cg_fused_kernel(
    const float* __restrict__ x,
    float* __restrict__ pub,              // [B*C][4] = (ar, ai, mr, mi)
    const float* __restrict__ w1r, const float* __restrict__ b1r,
    const float* __restrict__ w1i, const float* __restrict__ b1i,
    const float* __restrict__ w2r, const float* __restrict__ b2r,
    const float* __restrict__ w2i, const float* __restrict__ b2i,
    float* __restrict__ out)
{
    const int t = threadIdx.x;

    if (blockIdx.x >= NPOLL) {
        // ======================= WORKER: one (b,c) plane-pair ==============
        const int bc = blockIdx.x - NPOLL;    // 0 .. B*C-1
        const int b  = bc >> 9;               // / CC
        const int c  = bc & (CC - 1);
        const float* xr = x + (size_t)((b << 10) + c) * HWN;
        const float* xi = xr + (size_t)CC * HWN;
        const f32x4* xr4 = (const f32x4*)xr;
        const f32x4* xi4 = (const f32x4*)xi;

        float sr = 0.0f, si = 0.0f;
        float bs = -1.0f;                     // best score^2 (>=0 always wins)
        int   bix = 0x7fffffff;
        float br = 0.0f, bq = 0.0f;           // carried values at best index

        for (int v = t; v < HW4; v += 256) {
            f32x4 r4 = __builtin_nontemporal_load(&xr4[v]);
            f32x4 i4 = __builtin_nontemporal_load(&xi4[v]);
#pragma unroll
            for (int k = 0; k < 4; ++k) {
                float r = r4[k], q = i4[k];
                sr += r; si += q;
                float r2 = r * r, q2 = q * q;
                float d  = r2 + q2;
                float u  = __builtin_amdgcn_rcpf(d);   // argmax only
                float s  = fmaf(fmaf(d, u, 2.0f * (r2 - q2)), u, d);
                int idx  = v * 4 + k;
                if (s > bs) { bs = s; bix = idx; br = r; bq = q; }
            }
        }

        // wave reduce; ties -> min index (jnp.argmax first-hit)
#pragma unroll
        for (int off = 32; off > 0; off >>= 1) {
            sr += __shfl_down(sr, off);
            si += __shfl_down(si, off);
            float os = __shfl_down(bs, off);
            int   oi = __shfl_down(bix, off);
            float orr = __shfl_down(br, off);
            float oq  = __shfl_down(bq, off);
            if (os > bs || (os == bs && oi < bix)) { bs = os; bix = oi; br = orr; bq = oq; }
        }

        __shared__ float lsr[4], lsi[4], lbs[4], lbr[4], lbq[4];
        __shared__ int   lbi[4];
        const int wave = t >> 6;
        if ((t & 63) == 0) {
            lsr[wave] = sr; lsi[wave] = si; lbs[wave] = bs;
            lbi[wave] = bix; lbr[wave] = br; lbq[wave] = bq;
        }
        __syncthreads();

        if (t == 0) {
            sr = lsr[0]; si = lsi[0]; bs = lbs[0]; bix = lbi[0]; br = lbr[0]; bq = lbq[0];
#pragma unroll
            for (int w = 1; w < 4; ++w) {
                sr += lsr[w]; si += lsi[w];
                if (lbs[w] > bs || (lbs[w] == bs && lbi[w] < bix)) {
                    bs = lbs[w]; bix = lbi[w]; br = lbr[w]; bq = lbq[w];
                }
            }
            // fire-and-forget publish: no waitcnt, no RMW, no broadcast
            float* q = pub + (size_t)bc * 4;
            __hip_atomic_store(&q[0], sr * (1.0f / HWN), __ATOMIC_RELAXED, AGENT);
            __hip_atomic_store(&q[1], si * (1.0f / HWN), __ATOMIC_RELAXED, AGENT);
            __hip_atomic_store(&q[2], br,                __ATOMIC_RELAXED, AGENT);
            __hip_atomic_store(&q[3], bq,                __ATOMIC_RELAXED, AGENT);
        }
        return;   // stores complete after endpgm; block retires at full pace
    }

    // ======================= POLLER: batch b = blockIdx.x ==================
    const int b = blockIdx.x;
    __shared__ __align__(16) float s_re[2][CC], s_im[2][CC];
    __shared__ float h_re[2][CR], h_im[2][CR];

    for (int k = t; k < CC; k += 256) {
        const uint32_t* q = (const uint32_t*)(pub + (size_t)(b * CC + k) * 4);
        s_re[0][k] = spin_word(q + 0);    // ar
        s_im[0][k] = spin_word(q + 1);    // ai
        s_re[1][k] = spin_word(q + 2);    // mr
        s_im[1][k] = spin_word(q + 3);    // mi
    }
    __syncthreads();

    // ---- layer 1 + cardioid: 64 tasks (m,j), 4 threads per task ----
    {
        const int task = t >> 2;          // 0..63
        const int part = t & 3;
        const int m = task >> 5;          // which MLP input (mean / max)
        const int j = task & 31;          // hidden unit
        const float* wr = w1r + j * CC + part * 128;
        const float* wi = w1i + j * CC + part * 128;
        const float* re_ = &s_re[m][part * 128];
        const float* im_ = &s_im[m][part * 128];
        float d_rr = 0.f, d_ir = 0.f, d_ri = 0.f, d_ii = 0.f;
#pragma unroll 4
        for (int k = 0; k < 128; ++k) {
            float re = re_[k], im = im_[k];
            float vr = wr[k], vi = wi[k];
            d_rr += re * vr;
            d_ir += im * vr;
            d_ri += re * vi;
            d_ii += im * vi;
        }
        d_rr += __shfl_xor(d_rr, 1); d_rr += __shfl_xor(d_rr, 2);
        d_ir += __shfl_xor(d_ir, 1); d_ir += __shfl_xor(d_ir, 2);
        d_ri += __shfl_xor(d_ri, 1); d_ri += __shfl_xor(d_ri, 2);
        d_ii += __shfl_xor(d_ii, 1); d_ii += __shfl_xor(d_ii, 2);
        if (part == 0) {
            float hre = d_rr + b1r[j] - d_ii - b1i[j];
            float him = d_ir + b1r[j] + d_ri + b1i[j];
            // cardioid: s = 0.5*(1 + cos(atan2(im,re))) = 0.5*(1 + re/|z|)
            float n2 = hre * hre + him * him;
            float s  = (n2 > 0.0f) ? 0.5f * (1.0f + hre * rsqrtf(n2)) : 1.0f;
            h_re[m][j] = hre * s;
            h_im[m][j] = him * s;
        }
    }
    __syncthreads();

    // ---- layer 2 (summed over both MLPs) ----
    for (int j = t; j < CC; j += 256) {
        float o_re = 2.0f * (b2r[j] - b2i[j]);   // bias applied per MLP (x2)
        float o_im = 2.0f * (b2r[j] + b2i[j]);
        const float* wr = w2r + j * CR;
        const float* wi = w2i + j * CR;
#pragma unroll
        for (int m = 0; m < 2; ++m) {
            const float* hr_ = h_re[m];
            const float* hi_ = h_im[m];
#pragma unroll 8
            for (int k = 0; k < CR; ++k) {
                float hr = hr_[k], hi = hi_[k];
                float vr = wr[k], vi = wi[k];
                o_re += hr * vr - hi * vi;
                o_im += hi * vr + hr * vi;
            }
        }
        out[b * 2 * CC + j]      = o_re;
        out[b * 2 * CC + CC + j] = o_im;
    }
}

extern "C" void kernel_launch(void* const* d_in, const int* in_sizes, int n_in,
                              void* d_out, int out_size, void* d_ws, size_t ws_size,
                              hipStream_t stream)
{
    const float* x   = (const float*)d_in[0];
    const float* w1r = (const float*)d_in[1];
    const float* b1r = (const float*)d_in[2];
    const float* w1i = (const float*)d_in[3];
    const float* b1i = (const float*)d_in[4];
    const float* w2r = (const float*)d_in[5];
    const float* b2r = (const float*)d_in[6];
    const float* w2i = (const float*)d_in[7];
    const float* b2i = (const float*)d_in[8];

    float* pub = (float*)d_ws;                       // [B*C][4]
    const size_t pub_bytes = (size_t)BB * CC * 4 * sizeof(float);  // 256 KB

    hipMemsetAsync(pub, 0xFF, pub_bytes, stream);    // sentinel = 0xFFFFFFFF
    cg_fused_kernel<<<NPOLL + BB * CC, 256, 0, stream>>>(
        x, pub,
        w1r, b1r, w1i, b1i,
        w2r, b2r, w2i, b2i,
        (float*)d_out);
}

// Round 10
// 79.728 us; speedup vs baseline: 9.4525x; 1.1218x over previous
//
#include <hip/hip_runtime.h>
#include <math.h>

#define BB 32
#define CC 512
#define CR 32
#define HWN 3136
#define HW4 784   // HWN / 4

typedef float f32x4 __attribute__((ext_vector_type(4)));

// ---------------------------------------------------------------------------
// FINAL FORM: two kernels (R2-proven structure, 78.6us).
// Fusion attempts R4-R8 (threadfence / counter / fire-and-forget+poller) all
// regressed: threadfence = per-block L2 cache walks (753us); fused register
// pressure = 104 VGPR -> occupancy cliff (168us); capped VGPR fused = 89us.
// Two dispatches win: worker kernel stays at 8 waves/SIMD with zero epilogue
// waiting, MLP kernel pays one ~2us graph-node gap.
//
// Kernel 1: block per (b,c) plane-pair:
//   - plane sums -> ar/ai means
//   - argmax of score^2 = zr^2+zi^2 (sqrt monotonic -> dropped), with the
//     best (r,q) VALUES carried through the reduce (no end-of-block gather;
//     under nt loads that gather was an HBM round-trip in every block tail)
//   - score^2 = fma(fma(d,u, 2(r^2-q^2)), u, d), u = rcp(d), d = r^2+q^2
//     (1-ulp rcp feeds the argmax comparison only; outputs stay exact)
// ---------------------------------------------------------------------------
__global__ __launch_bounds__(256) void cg_reduce_kernel(
    const float* __restrict__ x,
    float* __restrict__ ar, float* __restrict__ ai,
    float* __restrict__ mr, float* __restrict__ mi)
{
    const int bc = blockIdx.x;            // 0 .. B*C-1
    const int b  = bc >> 9;               // / CC
    const int c  = bc & (CC - 1);
    const float* xr = x + (size_t)((b << 10) + c) * HWN;   // (b*2C + c)*HWN
    const float* xi = xr + (size_t)CC * HWN;
    const f32x4* xr4 = (const f32x4*)xr;
    const f32x4* xi4 = (const f32x4*)xi;
    const int t = threadIdx.x;

    float sr = 0.0f, si = 0.0f;
    float bs = -1.0f;                     // best score^2 (>=0 always wins)
    int   bix = 0x7fffffff;
    float br = 0.0f, bq = 0.0f;           // carried values at best index

    for (int v = t; v < HW4; v += 256) {
        f32x4 r4 = __builtin_nontemporal_load(&xr4[v]);
        f32x4 i4 = __builtin_nontemporal_load(&xi4[v]);
#pragma unroll
        for (int k = 0; k < 4; ++k) {
            float r = r4[k], q = i4[k];
            sr += r; si += q;
            float r2 = r * r, q2 = q * q;
            float d  = r2 + q2;
            float u  = __builtin_amdgcn_rcpf(d);
            float s  = fmaf(fmaf(d, u, 2.0f * (r2 - q2)), u, d);
            int idx  = v * 4 + k;         // strictly increasing per thread
            if (s > bs) { bs = s; bix = idx; br = r; bq = q; }
        }
    }

    // wave-level reduce (wave = 64); ties -> min index (jnp first-hit)
#pragma unroll
    for (int off = 32; off > 0; off >>= 1) {
        sr += __shfl_down(sr, off);
        si += __shfl_down(si, off);
        float os = __shfl_down(bs, off);
        int   oi = __shfl_down(bix, off);
        float orr = __shfl_down(br, off);
        float oq  = __shfl_down(bq, off);
        if (os > bs || (os == bs && oi < bix)) { bs = os; bix = oi; br = orr; bq = oq; }
    }

    __shared__ float lsr[4], lsi[4], lbs[4], lbr[4], lbq[4];
    __shared__ int   lbi[4];
    const int wave = t >> 6;
    if ((t & 63) == 0) {
        lsr[wave] = sr; lsi[wave] = si; lbs[wave] = bs;
        lbi[wave] = bix; lbr[wave] = br; lbq[wave] = bq;
    }
    __syncthreads();

    if (t == 0) {
        sr = lsr[0]; si = lsi[0]; bs = lbs[0]; bix = lbi[0]; br = lbr[0]; bq = lbq[0];
#pragma unroll
        for (int w = 1; w < 4; ++w) {
            sr += lsr[w]; si += lsi[w];
            if (lbs[w] > bs || (lbs[w] == bs && lbi[w] < bix)) {
                bs = lbs[w]; bix = lbi[w]; br = lbr[w]; bq = lbq[w];
            }
        }
        ar[bc] = sr * (1.0f / HWN);
        ai[bc] = si * (1.0f / HWN);
        mr[bc] = br;                      // carried values: no gather
        mi[bc] = bq;
    }
}

// ---------------------------------------------------------------------------
// Kernel 2: both complex MLPs + sum, one block per batch row (vectorized).
//   att = MLP(ar,ai) + MLP(mr,mi);  out[b, 0:C] = re, out[b, C:2C] = im
// ---------------------------------------------------------------------------
__global__ __launch_bounds__(256) void cg_mlp_kernel(
    const float* __restrict__ ar, const float* __restrict__ ai,
    const float* __restrict__ mr, const float* __restrict__ mi,
    const float* __restrict__ w1r, const float* __restrict__ b1r,
    const float* __restrict__ w1i, const float* __restrict__ b1i,
    const float* __restrict__ w2r, const float* __restrict__ b2r,
    const float* __restrict__ w2i, const float* __restrict__ b2i,
    float* __restrict__ out)
{
    __shared__ __align__(16) float s_re[2][CC], s_im[2][CC];
    __shared__ float h_re[2][CR], h_im[2][CR];

    const int b = blockIdx.x;
    const int t = threadIdx.x;

    if (t < 128) {
        ((f32x4*)s_re[0])[t] = ((const f32x4*)(ar + b * CC))[t];
        ((f32x4*)s_im[0])[t] = ((const f32x4*)(ai + b * CC))[t];
        ((f32x4*)s_re[1])[t] = ((const f32x4*)(mr + b * CC))[t];
        ((f32x4*)s_im[1])[t] = ((const f32x4*)(mi + b * CC))[t];
    }
    __syncthreads();

    // ---- layer 1 + cardioid: 64 tasks (m,j), 4 threads per task ----
    {
        const int task = t >> 2;          // 0..63
        const int part = t & 3;
        const int m = task >> 5;          // which MLP input (mean / max)
        const int j = task & 31;          // hidden unit
        const f32x4* wr4 = (const f32x4*)(w1r + j * CC + part * 128);
        const f32x4* wi4 = (const f32x4*)(w1i + j * CC + part * 128);
        const f32x4* re4 = (const f32x4*)(&s_re[m][part * 128]);
        const f32x4* im4 = (const f32x4*)(&s_im[m][part * 128]);
        float d_rr = 0.f, d_ir = 0.f, d_ri = 0.f, d_ii = 0.f;
#pragma unroll 8
        for (int k = 0; k < 32; ++k) {
            f32x4 re = re4[k], im = im4[k], vr = wr4[k], vi = wi4[k];
#pragma unroll
            for (int kk = 0; kk < 4; ++kk) {
                d_rr += re[kk] * vr[kk];
                d_ir += im[kk] * vr[kk];
                d_ri += re[kk] * vi[kk];
                d_ii += im[kk] * vi[kk];
            }
        }
        d_rr += __shfl_xor(d_rr, 1); d_rr += __shfl_xor(d_rr, 2);
        d_ir += __shfl_xor(d_ir, 1); d_ir += __shfl_xor(d_ir, 2);
        d_ri += __shfl_xor(d_ri, 1); d_ri += __shfl_xor(d_ri, 2);
        d_ii += __shfl_xor(d_ii, 1); d_ii += __shfl_xor(d_ii, 2);
        if (part == 0) {
            float hre = d_rr + b1r[j] - d_ii - b1i[j];
            float him = d_ir + b1r[j] + d_ri + b1i[j];
            // cardioid: s = 0.5*(1 + cos(atan2(im,re))) = 0.5*(1 + re/|z|)
            float n2 = hre * hre + him * him;
            float s  = (n2 > 0.0f) ? 0.5f * (1.0f + hre * rsqrtf(n2)) : 1.0f;
            h_re[m][j] = hre * s;
            h_im[m][j] = him * s;
        }
    }
    __syncthreads();

    // ---- layer 2 (summed over both MLPs) ----
    for (int j = t; j < CC; j += 256) {
        float o_re = 2.0f * (b2r[j] - b2i[j]);   // bias applied per MLP (x2)
        float o_im = 2.0f * (b2r[j] + b2i[j]);
        const f32x4* wr4 = (const f32x4*)(w2r + j * CR);
        const f32x4* wi4 = (const f32x4*)(w2i + j * CR);
#pragma unroll
        for (int m = 0; m < 2; ++m) {
            const float* hr_ = h_re[m];
            const float* hi_ = h_im[m];
#pragma unroll
            for (int kv = 0; kv < 8; ++kv) {
                f32x4 vr = wr4[kv], vi = wi4[kv];
#pragma unroll
                for (int kk = 0; kk < 4; ++kk) {
                    float hr = hr_[kv * 4 + kk], hi = hi_[kv * 4 + kk];
                    o_re += hr * vr[kk] - hi * vi[kk];
                    o_im += hi * vr[kk] + hr * vi[kk];
                }
            }
        }
        out[b * 2 * CC + j]      = o_re;
        out[b * 2 * CC + CC + j] = o_im;
    }
}

extern "C" void kernel_launch(void* const* d_in, const int* in_sizes, int n_in,
                              void* d_out, int out_size, void* d_ws, size_t ws_size,
                              hipStream_t stream)
{
    const float* x   = (const float*)d_in[0];
    const float* w1r = (const float*)d_in[1];
    const float* b1r = (const float*)d_in[2];
    const float* w1i = (const float*)d_in[3];
    const float* b1i = (const float*)d_in[4];
    const float* w2r = (const float*)d_in[5];
    const float* b2r = (const float*)d_in[6];
    const float* w2i = (const float*)d_in[7];
    const float* b2i = (const float*)d_in[8];

    float* ws = (float*)d_ws;
    float* ar = ws;
    float* ai = ws +     BB * CC;
    float* mr = ws + 2 * BB * CC;
    float* mi = ws + 3 * BB * CC;

    cg_reduce_kernel<<<BB * CC, 256, 0, stream>>>(x, ar, ai, mr, mi);
    cg_mlp_kernel<<<BB, 256, 0, stream>>>(ar, ai, mr, mi,
                                          w1r, b1r, w1i, b1i,
                                          w2r, b2r, w2i, b2i,
                                          (float*)d_out);
}